// Round 2
// baseline (402.947 us; speedup 1.0000x reference)
//
#include <hip/hip_runtime.h>
#include <hip/hip_bf16.h>

// ---------------------------------------------------------------------------
// WindowShiftedMDTA fused kernel (MI355X / gfx950).
//
// Math fact: with shift = window/2 the reference's shift-mask is all ones, so
// the shifted branch is multiplied by zero => output == unshifted branch only.
//
// Dtype fact (round-1 post-mortem): device buffers are fp32 (reference dtype).
// We compute in bf16 MFMA (2%-of-max threshold tolerates it), fp32 I/O.
//
// One workgroup per 8x8 window (1152 WGs), 4 waves, ~152KB dynamic LDS.
//   MFMA v_mfma_f32_16x16x32_bf16:
//   C/D: col = lane&15, row = (lane>>4)*4 + reg      (m89-verified)
//   A:   row = lane&15, k = (lane>>4)*8 + j
//   B:   col = lane&15, k = (lane>>4)*8 + j
// ---------------------------------------------------------------------------

typedef short bf16x8 __attribute__((ext_vector_type(8)));
typedef float f32x4 __attribute__((ext_vector_type(4)));

#define MFMA16(A_, B_, C_) __builtin_amdgcn_mfma_f32_16x16x32_bf16((A_), (B_), (C_), 0, 0, 0)

__device__ __forceinline__ short f2b(float f) {
  __hip_bfloat16 h = __float2bfloat16(f);   // RNE; compiler fuses to v_cvt_pk_bf16_f32
  return __builtin_bit_cast(short, h);
}

// ---- LDS byte-offset map (total 155648 B) ---------------------------------
// [0,      32768)  x_q tile [256 c][64 pos] bf16, 16B blocks swizzled by (c>>3)&7.
//                  After q-GEMM re-used as qT per wave/head: wv*8192 + h2*4096,
//                  layout [64 n][32 d], 16B blk ^= (n&3).
// [32768,  65536)  x_kv tile, same layout as x_q.
// [65536,  86016)  a_lds: 4 slots [64 pos][40 d] bf16 (slot = wave).
// [86016, 155648)  per-wave 17408B: kT [64][40] bf16 (5120) | v [32][64] bf16
//                  blk^=(d&7) (4096) | P [64][64] bf16 blk^=(n&7) (8192).
//                  Re-used as o_lds [64 ch][68 f32] in the epilogue (17408 B).
constexpr unsigned XQ_OFF  = 0u;
constexpr unsigned XKV_OFF = 32768u;
constexpr unsigned A_OFF   = 65536u;
constexpr unsigned PW_OFF  = 86016u;
constexpr unsigned PW_SZ   = 17408u;
constexpr int SMEM_BYTES   = 155648;

// MFMA fragment of the staged x tile: element j = x[c0+j][pos].
// A-frag (rows = pos) for qT/kT GEMMs; B-frag (cols = pos) for v GEMM.
__device__ __forceinline__ bf16x8 xfrag(const char* smem, unsigned toff, int ks, int pb, int lane) {
  const int pos = pb * 16 + (lane & 15);
  const int c0  = ks * 32 + ((lane >> 4) << 3);      // 8-aligned -> swizzle j-invariant
  const unsigned colsw = ((((unsigned)pos >> 3) ^ (((unsigned)c0 >> 3) & 7u)) << 4)
                       + (unsigned)((pos & 7) * 2);
  bf16x8 f;
  #pragma unroll
  for (int j = 0; j < 8; ++j)
    f[j] = *(const short*)(smem + toff + (unsigned)((c0 + j) * 128) + colsw);
  return f;
}

// 8 consecutive fp32 weights -> bf16 MFMA fragment (32B aligned).
__device__ __forceinline__ bf16x8 wfrag(const float* p) {
  const float4 a = *(const float4*)p;
  const float4 b = *(const float4*)(p + 4);
  bf16x8 f;
  f[0] = f2b(a.x); f[1] = f2b(a.y); f[2] = f2b(a.z); f[3] = f2b(a.w);
  f[4] = f2b(b.x); f[5] = f2b(b.y); f[6] = f2b(b.z); f[7] = f2b(b.w);
  return f;
}

__global__ __launch_bounds__(256, 1) void wsmdta_fused(
    const float* __restrict__ xq, const float* __restrict__ xkv,
    const float* __restrict__ temp,
    const float* __restrict__ Wq, const float* __restrict__ Wk,
    const float* __restrict__ Wv, const float* __restrict__ Wo,
    float* __restrict__ out)
{
  extern __shared__ __align__(16) char smem[];
  const int tid = threadIdx.x, lane = tid & 63, wv = tid >> 6;

  // XCD-bijective swizzle (1152 = 8 XCD * 144): 144 consecutive windows / XCD.
  const int bid = blockIdx.x;
  const int wid = (bid & 7) * 144 + (bid >> 3);
  const int b  = wid / 576, rw = wid - b * 576;
  const int wh = rw / 24,   ww = rw - wh * 24;
  const int xoff = wh * 8 * 192 + ww * 8;          // window origin (elements)
  const size_t ibase = (size_t)b * 9437184;        // b * 256 * 36864

  const f32x4 fzero = {0.f, 0.f, 0.f, 0.f};

  // ---- stage both x windows: fp32 global -> bf16 LDS ----------------------
  #pragma unroll
  for (int j = 0; j < 8; ++j) {
    const int u = j * 256 + tid;                   // 2048 8-elem blocks / tensor
    const int c = u >> 3, hb = u & 7;              // hb = window row
    const unsigned dst = (unsigned)(c * 128 + ((hb ^ ((c >> 3) & 7)) << 4));
    const size_t g = ibase + (size_t)c * 36864 + (size_t)(xoff + hb * 192);
    const float4 q0 = *(const float4*)(xq + g), q1 = *(const float4*)(xq + g + 4);
    const float4 k0 = *(const float4*)(xkv + g), k1 = *(const float4*)(xkv + g + 4);
    bf16x8 bq, bk;
    bq[0] = f2b(q0.x); bq[1] = f2b(q0.y); bq[2] = f2b(q0.z); bq[3] = f2b(q0.w);
    bq[4] = f2b(q1.x); bq[5] = f2b(q1.y); bq[6] = f2b(q1.z); bq[7] = f2b(q1.w);
    bk[0] = f2b(k0.x); bk[1] = f2b(k0.y); bk[2] = f2b(k0.z); bk[3] = f2b(k0.w);
    bk[4] = f2b(k1.x); bk[5] = f2b(k1.y); bk[6] = f2b(k1.z); bk[7] = f2b(k1.w);
    *(bf16x8*)(smem + XQ_OFF  + dst) = bq;
    *(bf16x8*)(smem + XKV_OFF + dst) = bk;
  }
  __syncthreads();

  const float tm0 = temp[wv * 2 + 0];
  const float tm1 = temp[wv * 2 + 1];

  // ---- q GEMMs for this wave's two heads: qT[n][d] = sum_c xT[n][c]*Wq[h*32+d][c]
  f32x4 qa[2][4][2];
  #pragma unroll
  for (int h2 = 0; h2 < 2; ++h2)
    #pragma unroll
    for (int pb = 0; pb < 4; ++pb)
      #pragma unroll
      for (int dj = 0; dj < 2; ++dj) qa[h2][pb][dj] = fzero;

  #pragma unroll
  for (int ks = 0; ks < 8; ++ks) {
    bf16x8 xf[4];
    #pragma unroll
    for (int pb = 0; pb < 4; ++pb) xf[pb] = xfrag(smem, XQ_OFF, ks, pb, lane);
    bf16x8 wf[2][2];                               // B frag from L2-resident Wq (fp32->bf16)
    #pragma unroll
    for (int h2 = 0; h2 < 2; ++h2)
      #pragma unroll
      for (int dj = 0; dj < 2; ++dj) {
        const int row = (wv * 2 + h2) * 32 + dj * 16 + (lane & 15);
        wf[h2][dj] = wfrag(Wq + row * 256 + ks * 32 + ((lane >> 4) << 3));
      }
    #pragma unroll
    for (int h2 = 0; h2 < 2; ++h2)
      #pragma unroll
      for (int pb = 0; pb < 4; ++pb)
        #pragma unroll
        for (int dj = 0; dj < 2; ++dj)
          qa[h2][pb][dj] = MFMA16(xf[pb], wf[h2][dj], qa[h2][pb][dj]);
  }
  __syncthreads();   // everyone done reading x_q before qT overwrites it

  // qT write: [64 n][32 d], 16B blk ^= (n&3)
  #pragma unroll
  for (int h2 = 0; h2 < 2; ++h2)
    #pragma unroll
    for (int pb = 0; pb < 4; ++pb)
      #pragma unroll
      for (int dj = 0; dj < 2; ++dj)
        #pragma unroll
        for (int r = 0; r < 4; ++r) {
          const int n = pb * 16 + ((lane >> 4) << 2) + r;
          const int d = dj * 16 + (lane & 15);
          const unsigned a = XQ_OFF + (unsigned)(wv * 8192 + h2 * 4096)
                           + (unsigned)(n * 64)
                           + (((unsigned)(d >> 3) ^ (unsigned)(n & 3)) << 4)
                           + (unsigned)((d & 7) * 2);
          *(short*)(smem + a) = f2b(qa[h2][pb][dj][r]);
        }

  const unsigned kTb = PW_OFF + (unsigned)wv * PW_SZ;
  const unsigned vB  = kTb + 5120u;
  const unsigned pB  = kTb + 9216u;

  f32x4 oacc[4][4];
  #pragma unroll
  for (int mi = 0; mi < 4; ++mi)
    #pragma unroll
    for (int nj = 0; nj < 4; ++nj) oacc[mi][nj] = fzero;

  #pragma unroll
  for (int hr = 0; hr < 2; ++hr) {
    const int h = wv * 2 + hr;
    const float tm = hr ? tm1 : tm0;

    // ---- k & v GEMMs for head h ----------------------------------------
    f32x4 ka[4][2], va[2][4];
    #pragma unroll
    for (int pb = 0; pb < 4; ++pb) { ka[pb][0] = fzero; ka[pb][1] = fzero; }
    #pragma unroll
    for (int mjj = 0; mjj < 4; ++mjj) { va[0][mjj] = fzero; va[1][mjj] = fzero; }

    #pragma unroll
    for (int ks = 0; ks < 8; ++ks) {
      bf16x8 xf[4];
      #pragma unroll
      for (int pb = 0; pb < 4; ++pb) xf[pb] = xfrag(smem, XKV_OFF, ks, pb, lane);
      bf16x8 wkf[2], wvf[2];
      #pragma unroll
      for (int dj = 0; dj < 2; ++dj) {
        const int row = h * 32 + dj * 16 + (lane & 15);
        wkf[dj] = wfrag(Wk + row * 256 + ks * 32 + ((lane >> 4) << 3));
        wvf[dj] = wfrag(Wv + row * 256 + ks * 32 + ((lane >> 4) << 3));
      }
      #pragma unroll
      for (int pb = 0; pb < 4; ++pb)
        #pragma unroll
        for (int dj = 0; dj < 2; ++dj)
          ka[pb][dj] = MFMA16(xf[pb], wkf[dj], ka[pb][dj]);       // kT[m][d]
      #pragma unroll
      for (int dj = 0; dj < 2; ++dj)
        #pragma unroll
        for (int mjj = 0; mjj < 4; ++mjj)
          va[dj][mjj] = MFMA16(wvf[dj], xf[mjj], va[dj][mjj]);    // v[d][m]
    }

    // kT [64 m][40 d] bf16 (padded stride, no swizzle)
    #pragma unroll
    for (int pb = 0; pb < 4; ++pb)
      #pragma unroll
      for (int dj = 0; dj < 2; ++dj)
        #pragma unroll
        for (int r = 0; r < 4; ++r) {
          const int m = pb * 16 + ((lane >> 4) << 2) + r;
          const int d = dj * 16 + (lane & 15);
          *(short*)(smem + kTb + (unsigned)(m * 80 + d * 2)) = f2b(ka[pb][dj][r]);
        }
    // v [32 d][64 m] bf16, blk ^= (d&7)
    #pragma unroll
    for (int dj = 0; dj < 2; ++dj)
      #pragma unroll
      for (int mjj = 0; mjj < 4; ++mjj)
        #pragma unroll
        for (int r = 0; r < 4; ++r) {
          const int d = dj * 16 + ((lane >> 4) << 2) + r;
          const int m = mjj * 16 + (lane & 15);
          const unsigned a = vB + (unsigned)(d * 128)
                           + (((unsigned)(m >> 3) ^ (unsigned)(d & 7)) << 4)
                           + (unsigned)((m & 7) * 2);
          *(short*)(smem + a) = f2b(va[dj][mjj][r]);
        }

    // ---- S = qT . k  (16 MFMAs, K=32) ----------------------------------
    bf16x8 afq[4], bfk[4];
    #pragma unroll
    for (int ni = 0; ni < 4; ++ni) {
      const int n = ni * 16 + (lane & 15);
      afq[ni] = *(const bf16x8*)(smem + XQ_OFF + (unsigned)(wv * 8192 + hr * 4096)
                 + (unsigned)(n * 64)
                 + (((unsigned)(lane >> 4) ^ (unsigned)(n & 3)) << 4));
    }
    #pragma unroll
    for (int mj = 0; mj < 4; ++mj) {
      const int m = mj * 16 + (lane & 15);
      bfk[mj] = *(const bf16x8*)(smem + kTb + (unsigned)(m * 80) + ((unsigned)(lane >> 4) << 4));
    }
    f32x4 s[4][4];
    #pragma unroll
    for (int ni = 0; ni < 4; ++ni)
      #pragma unroll
      for (int mj = 0; mj < 4; ++mj)
        s[ni][mj] = MFMA16(afq[ni], bfk[mj], fzero);

    // ---- softmax over m (rows n); 1/rowsum deferred into PV epilogue ----
    #pragma unroll
    for (int ni = 0; ni < 4; ++ni)
      #pragma unroll
      for (int mj = 0; mj < 4; ++mj)
        #pragma unroll
        for (int r = 0; r < 4; ++r) s[ni][mj][r] *= tm;

    float rinv[4][4];
    #pragma unroll
    for (int ni = 0; ni < 4; ++ni) {
      #pragma unroll
      for (int r = 0; r < 4; ++r) {
        float mx = fmaxf(fmaxf(s[ni][0][r], s[ni][1][r]), fmaxf(s[ni][2][r], s[ni][3][r]));
        mx = fmaxf(mx, __shfl_xor(mx, 1));
        mx = fmaxf(mx, __shfl_xor(mx, 2));
        mx = fmaxf(mx, __shfl_xor(mx, 4));
        mx = fmaxf(mx, __shfl_xor(mx, 8));
        float sum = 0.f;
        #pragma unroll
        for (int mj = 0; mj < 4; ++mj) {
          const float p = __expf(s[ni][mj][r] - mx);
          s[ni][mj][r] = p;
          sum += p;
        }
        sum += __shfl_xor(sum, 1);
        sum += __shfl_xor(sum, 2);
        sum += __shfl_xor(sum, 4);
        sum += __shfl_xor(sum, 8);
        rinv[ni][r] = 1.f / sum;
      }
    }
    // P [64 n][64 m] bf16, blk ^= (n&7)
    #pragma unroll
    for (int ni = 0; ni < 4; ++ni)
      #pragma unroll
      for (int mj = 0; mj < 4; ++mj)
        #pragma unroll
        for (int r = 0; r < 4; ++r) {
          const int n = ni * 16 + ((lane >> 4) << 2) + r;
          const int m = mj * 16 + (lane & 15);
          const unsigned a = pB + (unsigned)(n * 128)
                           + (((unsigned)(m >> 3) ^ (unsigned)(n & 7)) << 4)
                           + (unsigned)((m & 7) * 2);
          *(short*)(smem + a) = f2b(s[ni][mj][r]);
        }

    // ---- PV: a[n][d] = sum_m P[n][m] * v[d][m]  (16 MFMAs) -------------
    f32x4 pv[4][2];
    #pragma unroll
    for (int ni = 0; ni < 4; ++ni) { pv[ni][0] = fzero; pv[ni][1] = fzero; }
    #pragma unroll
    for (int ks2 = 0; ks2 < 2; ++ks2) {
      bf16x8 pa[4], vf[2];
      #pragma unroll
      for (int ni = 0; ni < 4; ++ni) {
        const int n = ni * 16 + (lane & 15);
        pa[ni] = *(const bf16x8*)(smem + pB + (unsigned)(n * 128)
                  + (((unsigned)(ks2 * 4 + (lane >> 4)) ^ (unsigned)(n & 7)) << 4));
      }
      #pragma unroll
      for (int dj = 0; dj < 2; ++dj) {
        const int d = dj * 16 + (lane & 15);
        vf[dj] = *(const bf16x8*)(smem + vB + (unsigned)(d * 128)
                  + (((unsigned)(ks2 * 4 + (lane >> 4)) ^ (unsigned)(d & 7)) << 4));
      }
      #pragma unroll
      for (int ni = 0; ni < 4; ++ni)
        #pragma unroll
        for (int dj = 0; dj < 2; ++dj)
          pv[ni][dj] = MFMA16(pa[ni], vf[dj], pv[ni][dj]);
    }
    // a slot (normalized here): [64 pos][40 d] bf16
    #pragma unroll
    for (int ni = 0; ni < 4; ++ni)
      #pragma unroll
      for (int dj = 0; dj < 2; ++dj)
        #pragma unroll
        for (int r = 0; r < 4; ++r) {
          const int n = ni * 16 + ((lane >> 4) << 2) + r;
          const int d = dj * 16 + (lane & 15);
          *(short*)(smem + A_OFF + (unsigned)(wv * 5120 + n * 80 + d * 2))
              = f2b(pv[ni][dj][r] * rinv[ni][r]);
        }
    __syncthreads();

    // ---- partial out GEMM: K = the 4 heads computed this round ---------
    #pragma unroll
    for (int s4 = 0; s4 < 4; ++s4) {
      const int hs = s4 * 2 + hr;
      bf16x8 aw[4], ab[4];
      #pragma unroll
      for (int mi = 0; mi < 4; ++mi) {
        const int rowc = wv * 64 + mi * 16 + (lane & 15);
        aw[mi] = wfrag(Wo + rowc * 256 + hs * 32 + ((lane >> 4) << 3));
      }
      #pragma unroll
      for (int nj = 0; nj < 4; ++nj) {
        const int pos = nj * 16 + (lane & 15);
        ab[nj] = *(const bf16x8*)(smem + A_OFF + (unsigned)(s4 * 5120 + pos * 80)
                  + ((unsigned)(lane >> 4) << 4));
      }
      #pragma unroll
      for (int mi = 0; mi < 4; ++mi)
        #pragma unroll
        for (int nj = 0; nj < 4; ++nj)
          oacc[mi][nj] = MFMA16(aw[mi], ab[nj], oacc[mi][nj]);
    }
    __syncthreads();   // a_lds reused next round
  }

  // ---- epilogue: fp32 transpose through LDS, coalesced float4 stores -----
  const unsigned ob = kTb;          // per-wave region now dead; o_lds [64][68] f32
  #pragma unroll
  for (int mi = 0; mi < 4; ++mi)
    #pragma unroll
    for (int nj = 0; nj < 4; ++nj)
      #pragma unroll
      for (int r = 0; r < 4; ++r) {
        const int cl  = mi * 16 + ((lane >> 4) << 2) + r;
        const int pos = nj * 16 + (lane & 15);
        *(float*)(smem + ob + (unsigned)(cl * 272 + pos * 4)) = oacc[mi][nj][r];
      }
  #pragma unroll
  for (int i = 0; i < 16; ++i) {
    const int idx = i * 64 + lane;                 // 1024 float4-quads / wave
    const int cl = idx >> 4, q4 = idx & 15;
    const float4 vv = *(const float4*)(smem + ob + (unsigned)(cl * 272 + q4 * 16));
    const int prow = q4 >> 1, pcol = (q4 & 1) * 4; // 2 lanes complete a 32B row
    const size_t ge = ibase + (size_t)(wv * 64 + cl) * 36864
                    + (size_t)(xoff + prow * 192 + pcol);
    *(float4*)(out + ge) = vv;
  }
}

extern "C" void kernel_launch(void* const* d_in, const int* in_sizes, int n_in,
                              void* d_out, int out_size, void* d_ws, size_t ws_size,
                              hipStream_t stream) {
  (void)in_sizes; (void)n_in; (void)d_ws; (void)ws_size; (void)out_size;
  // >64KB dynamic LDS needs the opt-in attribute (idempotent, capture-safe).
  hipFuncSetAttribute((const void*)wsmdta_fused,
                      hipFuncAttributeMaxDynamicSharedMemorySize, SMEM_BYTES);
  wsmdta_fused<<<dim3(1152), dim3(256), SMEM_BYTES, stream>>>(
      (const float*)d_in[0],  // x_q
      (const float*)d_in[1],  // x_kv
      (const float*)d_in[2],  // temperature
      (const float*)d_in[3],  // Wq
      (const float*)d_in[4],  // Wk
      (const float*)d_in[5],  // Wv
      (const float*)d_in[6],  // Wo
      (float*)d_out);
}

// Round 6
// 275.682 us; speedup vs baseline: 1.4616x; 1.4616x over previous
//
#include <hip/hip_runtime.h>
#include <hip/hip_bf16.h>

// ---------------------------------------------------------------------------
// WindowShiftedMDTA fused kernel, v6 (MI355X / gfx950).
//
// Math fact: with shift = window/2 the reference's shift-mask is all ones =>
// output == unshifted branch only.  fp32 I/O, bf16 MFMA compute (validated
// round 2: absmax 4.9e-4 vs threshold 1.79e-3).
//
// v6 = v5 with the host-pass compile fix: MFMA_K16 is defined unconditionally
// (the __has_builtin probe is host/device-pass dependent and #error'd the host
// build).  Core idea unchanged: K=16 MFMA register chaining.  For 16x16x16
// MFMA the C/D quad (col = lane&15, rows = 4*(lane>>4)+r) IS an A/B fragment
// (row/col = lane&15, k = (lane>>4)*4 + j).  So qT = MFMA(Wq,x), kT =
// MFMA(Wk,x) feed S = MFMA(kT,qT) straight from registers; S feeds softmax
// (row-normalizer is lane-uniform since n = column); P feeds PV = MFMA(v,P)
// straight from registers.  q/k/P never touch LDS.  No inline asm, no manual
// fences.
//
// LDS 64KB -> 2 blocks/CU, 8 waves each => 4 waves/SIMD (4x round-2 occupancy).
//   [0, 32768): XA region. First 16KB = x staging half [64 pos][128 c]
//     col-major, elem (c,pos) at pos*256 + ((c>>3 ^ PI(pos))<<4) + (c&7)*2.
//     Later: a-exchange [64 pos][256 c], pos*512 + ((c>>3 ^ PI(pos))<<4)+(c&7)*2.
//   [32768, 65536): per-wave 4KB v tile [32 d][64 m]:
//     d*128 + ((m>>3 ^ (d&7))<<4) + (m&7)*2.
//   PI(p) = (p ^ (p>>3)) & 7  (keeps b64/b128 accesses at the bank floor).
// ---------------------------------------------------------------------------

typedef short bf16x4 __attribute__((ext_vector_type(4)));
typedef short bf16x8 __attribute__((ext_vector_type(8)));
typedef float f32x4  __attribute__((ext_vector_type(4)));
typedef unsigned short ushort_t;

// v_mfma_f32_16x16x16_bf16 (gfx950 ISA sec.10: A/B = 2 VGPRs = 4 bf16, C/D = 4).
// Builtin signature V4f V4s V4s V4f Ii Ii Ii. Defined unconditionally: target
// builtins inside __global__ bodies are deferred in the host pass (round-2
// precedent with mfma_f32_16x16x32_bf16).
#define MFMA_K16(A_, B_, C_) __builtin_amdgcn_mfma_f32_16x16x16bf16_1k((A_), (B_), (C_), 0, 0, 0)
#define MFMA_K32(A_, B_, C_) __builtin_amdgcn_mfma_f32_16x16x32_bf16((A_), (B_), (C_), 0, 0, 0)

__device__ __forceinline__ short f2b(float f) {
  __hip_bfloat16 h = __float2bfloat16(f);
  return __builtin_bit_cast(short, h);
}
__device__ __forceinline__ bf16x4 cvt4(f32x4 v, float sc) {
  bf16x4 r;
  r[0] = f2b(v[0] * sc); r[1] = f2b(v[1] * sc);
  r[2] = f2b(v[2] * sc); r[3] = f2b(v[3] * sc);
  return r;
}
__device__ __forceinline__ int PI(int p) { return (p ^ (p >> 3)) & 7; }

// 4 / 8 consecutive K-elements of a weight row as MFMA fragments.
template<bool B16>
__device__ __forceinline__ bf16x4 ldw4(const void* W, int row, int c0) {
  if constexpr (B16) {
    return *(const bf16x4*)((const ushort_t*)W + (row << 8) + c0);
  } else {
    const float4 x = *(const float4*)((const float*)W + (row << 8) + c0);
    bf16x4 f; f[0] = f2b(x.x); f[1] = f2b(x.y); f[2] = f2b(x.z); f[3] = f2b(x.w);
    return f;
  }
}
template<bool B16>
__device__ __forceinline__ bf16x8 ldw8(const void* W, int row, int c0) {
  if constexpr (B16) {
    return *(const bf16x8*)((const ushort_t*)W + (row << 8) + c0);
  } else {
    const float* p = (const float*)W + (row << 8) + c0;
    const float4 x = *(const float4*)p, y = *(const float4*)(p + 4);
    bf16x8 f;
    f[0] = f2b(x.x); f[1] = f2b(x.y); f[2] = f2b(x.z); f[3] = f2b(x.w);
    f[4] = f2b(y.x); f[5] = f2b(y.y); f[6] = f2b(y.z); f[7] = f2b(y.w);
    return f;
  }
}

constexpr int SMEM_BYTES = 65536;

__global__ void wconv(const float* __restrict__ a, const float* __restrict__ b,
                      const float* __restrict__ c, const float* __restrict__ d,
                      ushort_t* __restrict__ o) {
  const int gid = blockIdx.x * 256 + threadIdx.x;        // 65536 float4-quads
  const int which = gid >> 14;
  const int idx = (gid & 16383) * 4;
  const float* src = which == 0 ? a : which == 1 ? b : which == 2 ? c : d;
  const float4 v = *(const float4*)(src + idx);
  bf16x4 w; w[0] = f2b(v.x); w[1] = f2b(v.y); w[2] = f2b(v.z); w[3] = f2b(v.w);
  *(bf16x4*)(o + which * 65536 + idx) = w;
}

// Stage one 128-channel half of x into R ([64 pos][128 c] swizzled col-major).
__device__ __forceinline__ void stage_half(char* smem, const float* __restrict__ src,
                                           int coff, int tid, size_t ibase, int xoff) {
  #pragma unroll
  for (int j = 0; j < 2; ++j) {
    const int u = j * 512 + tid;                 // 1024 units = 128c x 8 rows
    const int c = u >> 3, hr = u & 7;
    const size_t gg = ibase + (size_t)(c + coff) * 36864 + (size_t)(xoff + hr * 192);
    const float4 a0 = *(const float4*)(src + gg);
    const float4 a1 = *(const float4*)(src + gg + 4);
    const float vv[8] = {a0.x, a0.y, a0.z, a0.w, a1.x, a1.y, a1.z, a1.w};
    #pragma unroll
    for (int w = 0; w < 8; ++w) {
      const int pos = hr * 8 + w;
      const unsigned ad = (unsigned)(pos * 256 + (((c >> 3) ^ PI(pos)) << 4) + (c & 7) * 2);
      *(short*)(smem + ad) = f2b(vv[w]);
    }
  }
}

// x fragment (B-operand, N=pos, k=4 channels): one ds_read_b64.
__device__ __forceinline__ bf16x4 xfrag(const char* smem, int ktl, int nt, int l15, int g) {
  const int pos = nt * 16 + l15;
  const unsigned ad = (unsigned)(pos * 256 + (((ktl * 2 + (g >> 1)) ^ PI(pos)) << 4) + (g & 1) * 8);
  return *(const bf16x4*)(smem + ad);
}

template<bool WB16>
__global__ __launch_bounds__(512, 4) void wsmdta_main(
    const float* __restrict__ xq, const float* __restrict__ xkv,
    const float* __restrict__ temp,
    const void* __restrict__ Wq, const void* __restrict__ Wk,
    const void* __restrict__ Wv, const void* __restrict__ Wo,
    float* __restrict__ out)
{
  extern __shared__ __align__(16) char smem[];
  const int tid = threadIdx.x, lane = tid & 63, wv = tid >> 6;
  const int l15 = lane & 15, g = lane >> 4;

  // XCD-bijective swizzle (1152 = 8 XCD * 144).
  const int bid = blockIdx.x;
  const int wid = (bid & 7) * 144 + (bid >> 3);
  const int b  = wid / 576, rw = wid - b * 576;
  const int wh = rw / 24,   ww = rw - wh * 24;
  const int xoff = wh * 1536 + ww * 8;
  const size_t ibase = (size_t)b * 9437184;

  const unsigned VB = 32768u + (unsigned)wv * 4096u;
  const f32x4 fzero = {0.f, 0.f, 0.f, 0.f};
  const int h = wv;                                      // head of this wave

  // ================= q = Wq . x_q  (qT C/D kept in registers) ==============
  f32x4 qcd[2][4];
  #pragma unroll
  for (int dj = 0; dj < 2; ++dj)
    #pragma unroll
    for (int nt = 0; nt < 4; ++nt) qcd[dj][nt] = fzero;

  #pragma unroll
  for (int half = 0; half < 2; ++half) {
    if (half) __syncthreads();                           // pt0 reads done
    stage_half(smem, xq, half * 128, tid, ibase, xoff);
    __syncthreads();                                     // staging visible
    const int cg = half * 128;
    #pragma unroll
    for (int ktl = 0; ktl < 8; ++ktl) {
      const bf16x4 w0 = ldw4<WB16>(Wq, h * 32 + l15,      cg + ktl * 16 + g * 4);
      const bf16x4 w1 = ldw4<WB16>(Wq, h * 32 + 16 + l15, cg + ktl * 16 + g * 4);
      #pragma unroll
      for (int nt = 0; nt < 4; ++nt) {
        const bf16x4 xf = xfrag(smem, ktl, nt, l15, g);
        qcd[0][nt] = MFMA_K16(w0, xf, qcd[0][nt]);       // C[d][pos]
        qcd[1][nt] = MFMA_K16(w1, xf, qcd[1][nt]);
      }
    }
    __syncthreads();                                     // reads done
  }
  // qT -> bf16 fragments (k = d = 4g+r matches A/B frag k = g*4+j).
  bf16x4 qb[2][4];
  #pragma unroll
  for (int dj = 0; dj < 2; ++dj)
    #pragma unroll
    for (int nt = 0; nt < 4; ++nt) qb[dj][nt] = cvt4(qcd[dj][nt], 1.f);

  // ================= k = Wk.x_kv, v = Wv.x_kv (shared x fragments) =========
  f32x4 kcd[2][4], vcd[2][4];
  #pragma unroll
  for (int dj = 0; dj < 2; ++dj)
    #pragma unroll
    for (int mt = 0; mt < 4; ++mt) { kcd[dj][mt] = fzero; vcd[dj][mt] = fzero; }

  #pragma unroll
  for (int half = 0; half < 2; ++half) {
    stage_half(smem, xkv, half * 128, tid, ibase, xoff);
    __syncthreads();                                     // staging visible
    const int cg = half * 128;
    #pragma unroll
    for (int ktl = 0; ktl < 8; ++ktl) {
      const bf16x4 wk0 = ldw4<WB16>(Wk, h * 32 + l15,      cg + ktl * 16 + g * 4);
      const bf16x4 wk1 = ldw4<WB16>(Wk, h * 32 + 16 + l15, cg + ktl * 16 + g * 4);
      const bf16x4 wv0 = ldw4<WB16>(Wv, h * 32 + l15,      cg + ktl * 16 + g * 4);
      const bf16x4 wv1 = ldw4<WB16>(Wv, h * 32 + 16 + l15, cg + ktl * 16 + g * 4);
      #pragma unroll
      for (int mt = 0; mt < 4; ++mt) {
        const bf16x4 xf = xfrag(smem, ktl, mt, l15, g);
        kcd[0][mt] = MFMA_K16(wk0, xf, kcd[0][mt]);      // C[d][m]
        kcd[1][mt] = MFMA_K16(wk1, xf, kcd[1][mt]);
        vcd[0][mt] = MFMA_K16(wv0, xf, vcd[0][mt]);
        vcd[1][mt] = MFMA_K16(wv1, xf, vcd[1][mt]);
      }
    }
    if (half == 0) __syncthreads();                      // pt0 reads done
  }

  bf16x4 kb[2][4];
  #pragma unroll
  for (int dj = 0; dj < 2; ++dj)
    #pragma unroll
    for (int mt = 0; mt < 4; ++mt) kb[dj][mt] = cvt4(kcd[dj][mt], 1.f);

  // v -> per-wave LDS tile [32 d][64 m] (wave-private; compiler orders DS ops).
  #pragma unroll
  for (int dj = 0; dj < 2; ++dj)
    #pragma unroll
    for (int mt = 0; mt < 4; ++mt) {
      const bf16x4 q = cvt4(vcd[dj][mt], 1.f);
      const int m = mt * 16 + l15;
      #pragma unroll
      for (int r = 0; r < 4; ++r) {
        const int d = dj * 16 + 4 * g + r;
        const unsigned ad = VB + (unsigned)(d * 128 + (((m >> 3) ^ (d & 7)) << 4) + (m & 7) * 2);
        *(short*)(smem + ad) = q[r];
      }
    }

  // ================= S = kT^T.qT in registers (K=16 x 2) ===================
  f32x4 s[4][4];
  #pragma unroll
  for (int mt = 0; mt < 4; ++mt)
    #pragma unroll
    for (int nt = 0; nt < 4; ++nt) {
      s[mt][nt] = MFMA_K16(kb[0][mt], qb[0][nt], fzero); // C[m][n]
      s[mt][nt] = MFMA_K16(kb[1][mt], qb[1][nt], s[mt][nt]);
    }

  // ================= softmax over m; P stays in registers ==================
  const float tm = temp[h];
  bf16x4 Pb[4][4];
  #pragma unroll
  for (int nt = 0; nt < 4; ++nt) {
    float mx = -1e30f;
    #pragma unroll
    for (int mt = 0; mt < 4; ++mt)
      #pragma unroll
      for (int r = 0; r < 4; ++r) {
        const float v = s[mt][nt][r] * tm;
        s[mt][nt][r] = v;
        mx = fmaxf(mx, v);
      }
    mx = fmaxf(mx, __shfl_xor(mx, 16));
    mx = fmaxf(mx, __shfl_xor(mx, 32));
    float sum = 0.f;
    #pragma unroll
    for (int mt = 0; mt < 4; ++mt)
      #pragma unroll
      for (int r = 0; r < 4; ++r) {
        const float p = __expf(s[mt][nt][r] - mx);
        s[mt][nt][r] = p;
        sum += p;
      }
    sum += __shfl_xor(sum, 16);
    sum += __shfl_xor(sum, 32);
    const float ri = 1.f / sum;
    #pragma unroll
    for (int mt = 0; mt < 4; ++mt) Pb[mt][nt] = cvt4(s[mt][nt], ri);
  }

  // ================= PV: aT = v.P (A = v from LDS, B = P regs) =============
  f32x4 pcd[2][4];
  #pragma unroll
  for (int dj = 0; dj < 2; ++dj)
    #pragma unroll
    for (int nt = 0; nt < 4; ++nt) pcd[dj][nt] = fzero;
  #pragma unroll
  for (int mt = 0; mt < 4; ++mt)
    #pragma unroll
    for (int dj = 0; dj < 2; ++dj) {
      const int d = dj * 16 + l15;
      const unsigned ad = VB + (unsigned)(d * 128 + (((mt * 2 + (g >> 1)) ^ (d & 7)) << 4) + (g & 1) * 8);
      const bf16x4 vf = *(const bf16x4*)(smem + ad);     // (row=d, k=m)
      #pragma unroll
      for (int nt = 0; nt < 4; ++nt)
        pcd[dj][nt] = MFMA_K16(vf, Pb[mt][nt], pcd[dj][nt]);  // C[d][n]
    }

  __syncthreads();   // all x-staging reads done everywhere; XA becomes a-LDS

  // a (normalized already via ri in P) -> a-LDS [64 pos][256 c], b64 writes.
  #pragma unroll
  for (int dj = 0; dj < 2; ++dj)
    #pragma unroll
    for (int nt = 0; nt < 4; ++nt) {
      const bf16x4 q = cvt4(pcd[dj][nt], 1.f);
      const int pos = nt * 16 + l15;
      const int c0 = h * 32 + dj * 16 + 4 * g;           // 4 consecutive c
      const unsigned ad = (unsigned)(pos * 512 + (((c0 >> 3) ^ PI(pos)) << 4) + (c0 & 7) * 2);
      *(bf16x4*)(smem + ad) = q;
    }
  __syncthreads();   // all heads' a ready

  // ================= out^T = a.Wo (K=256, MFMA K=32, b128 a-reads) =========
  f32x4 ocd[4][2];
  #pragma unroll
  for (int nt = 0; nt < 4; ++nt) { ocd[nt][0] = fzero; ocd[nt][1] = fzero; }
  #pragma unroll
  for (int ks = 0; ks < 8; ++ks) {
    const bf16x8 w0 = ldw8<WB16>(Wo, wv * 32 + l15,      ks * 32 + g * 8);
    const bf16x8 w1 = ldw8<WB16>(Wo, wv * 32 + 16 + l15, ks * 32 + g * 8);
    #pragma unroll
    for (int nt = 0; nt < 4; ++nt) {
      const int pos = nt * 16 + l15;
      const unsigned ad = (unsigned)(pos * 512 + (((ks * 4 + g) ^ PI(pos)) << 4));
      const bf16x8 af = *(const bf16x8*)(smem + ad);     // A: (row=pos, k=c)
      ocd[nt][0] = MFMA_K32(af, w0, ocd[nt][0]);         // C[pos][c_out]
      ocd[nt][1] = MFMA_K32(af, w1, ocd[nt][1]);
    }
  }

  // C/D: col = c_out (fixed/lane), rows = 4 consecutive pos -> float4 stores.
  #pragma unroll
  for (int nt = 0; nt < 4; ++nt)
    #pragma unroll
    for (int ct = 0; ct < 2; ++ct) {
      const int c_out = wv * 32 + ct * 16 + l15;
      const int h_out = nt * 2 + (g >> 1);
      const int w0 = 4 * (g & 1);
      float4 v;
      v.x = ocd[nt][ct][0]; v.y = ocd[nt][ct][1];
      v.z = ocd[nt][ct][2]; v.w = ocd[nt][ct][3];
      *(float4*)(out + ibase + (size_t)c_out * 36864 + (size_t)(xoff + h_out * 192 + w0)) = v;
    }
}

extern "C" void kernel_launch(void* const* d_in, const int* in_sizes, int n_in,
                              void* d_out, int out_size, void* d_ws, size_t ws_size,
                              hipStream_t stream) {
  (void)in_sizes; (void)n_in; (void)out_size;
  const float* xq   = (const float*)d_in[0];
  const float* xkv  = (const float*)d_in[1];
  const float* temp = (const float*)d_in[2];
  const float* Wq   = (const float*)d_in[3];
  const float* Wk   = (const float*)d_in[4];
  const float* Wv   = (const float*)d_in[5];
  const float* Wo   = (const float*)d_in[6];
  float* out = (float*)d_out;

  const bool wb16 = (ws_size >= 4u * 65536u * sizeof(ushort_t));
  if (wb16) {
    ushort_t* wsb = (ushort_t*)d_ws;
    wconv<<<dim3(256), dim3(256), 0, stream>>>(Wq, Wk, Wv, Wo, wsb);
    (void)hipFuncSetAttribute((const void*)&wsmdta_main<true>,
                              hipFuncAttributeMaxDynamicSharedMemorySize, SMEM_BYTES);
    wsmdta_main<true><<<dim3(1152), dim3(512), SMEM_BYTES, stream>>>(
        xq, xkv, temp, wsb, wsb + 65536, wsb + 131072, wsb + 196608, out);
  } else {
    (void)hipFuncSetAttribute((const void*)&wsmdta_main<false>,
                              hipFuncAttributeMaxDynamicSharedMemorySize, SMEM_BYTES);
    wsmdta_main<false><<<dim3(1152), dim3(512), SMEM_BYTES, stream>>>(
        xq, xkv, temp, Wq, Wk, Wv, Wo, out);
  }
}